// Round 4
// baseline (415.393 us; speedup 1.0000x reference)
//
#include <hip/hip_runtime.h>
#include <math.h>

// SSIM loss, fused single-pass. fp32 [32,1,1024,1024] x2 -> scalar.
// Separable 11x11 Gaussian of 5 fields {a,b,a2,b2,ab}.
// Round-4: 2 rows per barrier phase (69 barriers, was 138). Per-phase fixed
// costs (barrier skew, waitcnt drains) were ~46% of runtime in round 3.
//  - register-staged pipeline: loads for rows s+4,s+5 issued at phase of rows
//    s,s+1; committed to LDS one phase later -> vmcnt drains at barriers hit
//    loads issued a full phase (~4000cy) earlier.
//  - LDS rows hold (img1,img2) interleaved v2f; 11 ds_read_b64 per row.
//  - vertical conv: 11-slot register ring, static mod-11 (rows unrolled 22 at
//    a time so s%11 is compile-time).
// Tile 256 cols x 128 rows; grid 4x8x32 = 1024 blocks = 4/CU in one round.

typedef float v2f __attribute__((ext_vector_type(2)));

#define IMG_W 1024
#define IMG_H 1024
#define NIMG  32
#define TW    256
#define TH    128
#define HALO  5
#define KW    11
#define ROWS  (TH + 2*HALO)   // 138 staged rows (even; pairs never split)
#define NBLK  7               // 7*22 = 154 unrolled row slots, tail guarded off
#define SBP   272             // LDS row stride in v2f (266 used, padded)

#define C1f (0.01f * 0.01f)
#define C2f (0.03f * 0.03f)

struct GW { float w[KW]; };

__global__ __launch_bounds__(256, 2)
void ssim_main(const float* __restrict__ img1, const float* __restrict__ img2,
               double* __restrict__ acc_out, GW gw)
{
    alignas(16) __shared__ v2f sb[2][2][SBP];   // [buf][row parity][col]
    __shared__ float wsum[4];

    const int tid = threadIdx.x;
    const int c0 = blockIdx.x * TW;
    const int r0 = blockIdx.y * TH;
    const size_t imgoff = (size_t)blockIdx.z * (size_t)(IMG_W * IMG_H);
    const float* p1 = img1 + imgoff;
    const float* p2 = img2 + imgoff;

    // column predicates (uniform over rows)
    const int  gc_main  = c0 - HALO + tid;
    const bool cok_main = ((unsigned)gc_main < (unsigned)IMG_W);
    const int  gc_halo  = c0 - HALO + TW + tid;          // only tid<10 uses
    const bool cok_halo = (tid < 2 * HALO) && ((unsigned)gc_halo < (unsigned)IMG_W);

    float w[KW];
#pragma unroll
    for (int i = 0; i < KW; ++i) w[i] = gw.w[i];
    v2f w2[KW];
#pragma unroll
    for (int i = 0; i < KW; ++i) { w2[i].x = w[i]; w2[i].y = w[i]; }

    // vertical ring: mu=(m1,m2), sq=(Saa,Sbb), ab=Sab  -> 55 floats
    v2f accmu[KW], accsq[KW];
    float accab[KW];
#pragma unroll
    for (int j = 0; j < KW; ++j) {
        accmu[j] = (v2f)(0.f); accsq[j] = (v2f)(0.f); accab[j] = 0.f;
    }

    float lsum = 0.0f;

    // staging registers: two rows x [a_main, b_main, a_halo, b_halo]
    float st[2][4];

    auto issue1 = [&](int s, float* v) {      // global -> regs for staged row s
        const int gr = r0 + s - HALO;
        const bool rok = ((unsigned)gr < (unsigned)IMG_H);
        const float* row1 = p1 + (size_t)gr * IMG_W;
        const float* row2 = p2 + (size_t)gr * IMG_W;
        const bool okm = rok && cok_main;
        const bool okh = rok && cok_halo;
        v[0] = okm ? row1[gc_main] : 0.f;
        v[1] = okm ? row2[gc_main] : 0.f;
        v[2] = okh ? row1[gc_halo] : 0.f;
        v[3] = okh ? row2[gc_halo] : 0.f;
    };
    auto commit1 = [&](int s, const float* v) {   // regs -> LDS slot for row s
        v2f* dst = sb[(s >> 1) & 1][s & 1];
        v2f t; t.x = v[0]; t.y = v[1];
        dst[tid] = t;
        if (tid < 2 * HALO) { v2f t2; t2.x = v[2]; t2.y = v[3]; dst[TW + tid] = t2; }
    };

    // prologue: rows 0,1 into buf0; rows 2,3 in flight in regs
    issue1(0, st[0]); issue1(1, st[1]);
    commit1(0, st[0]); commit1(1, st[1]);
    issue1(2, st[0]); issue1(3, st[1]);

    for (int blk = 0; blk < NBLK; ++blk) {
        const int s_base = blk * 22;
#pragma unroll
        for (int t = 0; t < 22; ++t) {
            const int s = s_base + t;          // row index; u = t%11 compile-time
            const int u = t % 11;
            if ((t & 1) == 0) {
                if (s < ROWS) {                // uniform guard
                    __syncthreads();           // prior phase reads done
                    if (s + 2 < ROWS) {        // regs (1 phase old) -> LDS
                        commit1(s + 2, st[0]); commit1(s + 3, st[1]);
                    }
                    if (s + 4 < ROWS) {        // next row pair into regs
                        issue1(s + 4, st[0]); issue1(s + 5, st[1]);
                    }
                }
            }
            if (s < ROWS) {
                // horizontal 11-tap conv of the 5 fields over (img1,img2)
                const v2f* b = sb[(s >> 1) & 1][s & 1];
                v2f hmu = (v2f)(0.f), hsq = (v2f)(0.f);
                float hab = 0.f;
#pragma unroll
                for (int i = 0; i < KW; ++i) {
                    v2f E = b[tid + i];
                    v2f sq = E * E;
                    float ab = E.x * E.y;
                    hmu += w2[i] * E;
                    hsq += w2[i] * sq;
                    hab += w[i] * ab;
                }

                // vertical ring accumulate; slot j fresh-starts when k==0
#pragma unroll
                for (int j = 0; j < KW; ++j) {
                    const int k = (u - j + KW) % KW;   // compile-time
                    if (k == 0) {
                        accmu[j] = w2[0] * hmu; accsq[j] = w2[0] * hsq; accab[j] = w[0] * hab;
                    } else {
                        accmu[j] += w2[k] * hmu; accsq[j] += w2[k] * hsq; accab[j] += w[k] * hab;
                    }
                }

                // output row r = s-10 completes in slot (u+1)%11
                if (s >= 10) {
                    const int je = (u + 1) % KW;
                    v2f mu = accmu[je];
                    v2f sqv = accsq[je];
                    float cab = accab[je];
                    v2f mus = mu * mu;                 // (mu1^2, mu2^2)
                    float mu12 = mu.x * mu.y;
                    v2f sg = sqv - mus;                // (sigma1^2, sigma2^2)
                    float sg12 = cab - mu12;
                    float num = (2.0f * mu12 + C1f) * (2.0f * sg12 + C2f);
                    float den = (mus.x + mus.y + C1f) * (sg.x + sg.y + C2f);
                    lsum += num * __builtin_amdgcn_rcpf(den);
                }
            }
        }
    }

    // block reduction: wave shuffle then LDS across the 4 waves
    float v = lsum;
#pragma unroll
    for (int off = 32; off > 0; off >>= 1) v += __shfl_down(v, off);
    __syncthreads();
    if ((tid & 63) == 0) wsum[tid >> 6] = v;
    __syncthreads();
    if (tid == 0) {
        float bsum = wsum[0] + wsum[1] + wsum[2] + wsum[3];
        atomicAdd(acc_out, (double)bsum);
    }
}

__global__ void ssim_finalize(const double* __restrict__ acc, float* __restrict__ out)
{
    out[0] = 1.0f - (float)(acc[0] * (1.0 / ((double)NIMG * IMG_W * IMG_H)));
}

extern "C" void kernel_launch(void* const* d_in, const int* in_sizes, int n_in,
                              void* d_out, int out_size, void* d_ws, size_t ws_size,
                              hipStream_t stream)
{
    const float* img1 = (const float*)d_in[0];
    const float* img2 = (const float*)d_in[1];
    float* out = (float*)d_out;
    double* accbuf = (double*)d_ws;

    // Gaussian weights exactly as the reference: exp in f64, cast f32, normalize
    GW gw;
    {
        float g[KW];
        double s = 0.0;
        for (int i = 0; i < KW; ++i) {
            int x = i - KW / 2;
            g[i] = (float)exp(-(double)(x * x) / (2.0 * 1.5 * 1.5));
            s += (double)g[i];
        }
        for (int i = 0; i < KW; ++i) gw.w[i] = (float)((double)g[i] / s);
    }

    hipMemsetAsync(accbuf, 0, sizeof(double), stream);
    dim3 grid(IMG_W / TW, IMG_H / TH, NIMG);
    ssim_main<<<grid, 256, 0, stream>>>(img1, img2, accbuf, gw);
    ssim_finalize<<<1, 1, 0, stream>>>(accbuf, out);
}

// Round 5
// 363.391 us; speedup vs baseline: 1.1431x; 1.1431x over previous
//
#include <hip/hip_runtime.h>
#include <math.h>

// SSIM loss, fused single-pass. fp32 [32,1,1024,1024] x2 -> scalar.
// Separable 11x11 Gaussian of 5 fields {a,b,a2,b2,ab}.
// Round-5: register-pressure fix of the r3 structure. r1-r4 all showed
// VGPR_Count ~44-96 with >100 live floats -> the 55-float vertical ring was
// parked in AGPRs; each ring fma became accvgpr_read+fma+accvgpr_write
// (+110 VALU ops/step, measured busy 125us vs 75us floor). Changes:
//  - weights used DIRECTLY from the kernarg struct (SGPRs; v_fma_f32 takes
//    one SGPR operand) -- r4 wasted 33 VGPRs on w[]/w2[] copies.
//  - all-scalar math; LDS stays (img1,img2)-interleaved float2 for b64 reads.
//  - staging loads use clamped addresses + value select (no branches around
//    loads inside the pipelined region).
//  - 1 row per barrier phase (r3 beat r4's 2-row phases), loads issued 2
//    phases ahead of their LDS commit.
// Tile 256 cols x 128 rows; grid 4x8x32 = 1024 blocks = 4/CU in one round.

typedef float v2f __attribute__((ext_vector_type(2)));

#define IMG_W 1024
#define IMG_H 1024
#define NIMG  32
#define TW    256
#define TH    128
#define HALO  5
#define KW    11
#define ROWS  (TH + 2*HALO)   // 138 staged rows
#define NSO   13              // 13*11 = 143 unrolled steps, tail guarded off
#define SBP   268             // LDS row stride in v2f (266 used, 16B-pad)

#define C1f (0.01f * 0.01f)
#define C2f (0.03f * 0.03f)

struct GW { float w[KW]; };

__global__ __launch_bounds__(256, 2)
void ssim_main(const float* __restrict__ img1, const float* __restrict__ img2,
               double* __restrict__ acc_out, GW gw)
{
    alignas(16) __shared__ v2f sb[2][SBP];
    __shared__ float wsum[4];

    const int tid = threadIdx.x;
    const int c0 = blockIdx.x * TW;
    const int r0 = blockIdx.y * TH;
    const size_t imgoff = (size_t)blockIdx.z * (size_t)(IMG_W * IMG_H);
    const float* p1 = img1 + imgoff;
    const float* p2 = img2 + imgoff;

    // column geometry (uniform over rows); addresses clamped, OOB zeroed by select
    const int  gc_m   = c0 - HALO + tid;
    const int  gcc_m  = min(max(gc_m, 0), IMG_W - 1);
    const bool cok_m  = ((unsigned)gc_m < (unsigned)IMG_W);
    const int  gc_h   = c0 - HALO + TW + tid;            // used by tid<10
    const int  gcc_h  = min(max(gc_h, 0), IMG_W - 1);
    const bool cok_h  = (tid < 2 * HALO) && ((unsigned)gc_h < (unsigned)IMG_W);

    // vertical ring: 5 fields x 11 slots = 55 floats (must stay in arch VGPRs)
    float r_m1[KW], r_m2[KW], r_sa[KW], r_sb[KW], r_ab[KW];
#pragma unroll
    for (int j = 0; j < KW; ++j) {
        r_m1[j] = 0.f; r_m2[j] = 0.f; r_sa[j] = 0.f; r_sb[j] = 0.f; r_ab[j] = 0.f;
    }

    float lsum = 0.0f;

    // staging registers for one row: [a_main, b_main, a_halo, b_halo]
    float s0, s1, s2, s3;

    auto issue = [&](int s) {           // global -> regs for staged row s
        const int gr  = r0 + s - HALO;
        const bool rok = ((unsigned)gr < (unsigned)IMG_H);
        const size_t rbase = (size_t)min(max(gr, 0), IMG_H - 1) * IMG_W;
        float a0 = p1[rbase + gcc_m];
        float b0 = p2[rbase + gcc_m];
        float a1 = p1[rbase + gcc_h];
        float b1 = p2[rbase + gcc_h];
        const bool okm = rok && cok_m;
        const bool okh = rok && cok_h;
        s0 = okm ? a0 : 0.f;
        s1 = okm ? b0 : 0.f;
        s2 = okh ? a1 : 0.f;
        s3 = okh ? b1 : 0.f;
    };
    auto commit = [&](int s) {          // regs -> LDS buffer s&1
        v2f* dst = sb[s & 1];
        v2f t; t.x = s0; t.y = s1;
        dst[tid] = t;
        if (tid < 2 * HALO) { v2f t2; t2.x = s2; t2.y = s3; dst[TW + tid] = t2; }
    };

    issue(0); commit(0);    // row 0 straight to LDS
    issue(1);               // row 1 in flight in regs

    for (int so = 0; so < NSO; ++so) {
#pragma unroll
        for (int u = 0; u < KW; ++u) {
            const int s = so * KW + u;
            if (s < ROWS) {                 // uniform guard (tail steps dead)
                __syncthreads();            // phase s-1 reads done; buf (s+1)&1 free
                if (s + 1 < ROWS) commit(s + 1);
                if (s + 2 < ROWS) issue(s + 2);

                // horizontal 11-tap conv of the 5 fields (weights = SGPRs)
                const v2f* b = sb[s & 1];
                float hm1 = 0.f, hm2 = 0.f, hsa = 0.f, hsb = 0.f, hab = 0.f;
#pragma unroll
                for (int i = 0; i < KW; ++i) {
                    v2f E = b[tid + i];
                    const float a  = E.x;
                    const float bb = E.y;
                    const float wi = gw.w[i];
                    hm1 = __builtin_fmaf(wi, a, hm1);
                    hm2 = __builtin_fmaf(wi, bb, hm2);
                    hsa = __builtin_fmaf(wi, a * a, hsa);
                    hsb = __builtin_fmaf(wi, bb * bb, hsb);
                    hab = __builtin_fmaf(wi, a * bb, hab);
                }

                // vertical ring accumulate; slot j fresh-starts when k==0
#pragma unroll
                for (int j = 0; j < KW; ++j) {
                    const int k = (u - j + KW) % KW;   // compile-time after unroll
                    const float wk = gw.w[k];
                    if (k == 0) {
                        r_m1[j] = wk * hm1; r_m2[j] = wk * hm2;
                        r_sa[j] = wk * hsa; r_sb[j] = wk * hsb;
                        r_ab[j] = wk * hab;
                    } else {
                        r_m1[j] = __builtin_fmaf(wk, hm1, r_m1[j]);
                        r_m2[j] = __builtin_fmaf(wk, hm2, r_m2[j]);
                        r_sa[j] = __builtin_fmaf(wk, hsa, r_sa[j]);
                        r_sb[j] = __builtin_fmaf(wk, hsb, r_sb[j]);
                        r_ab[j] = __builtin_fmaf(wk, hab, r_ab[j]);
                    }
                }

                // output row r = s-10 completes in slot (u+1)%11
                if (s >= 10) {
                    const int je = (u + 1) % KW;
                    const float mu1 = r_m1[je], mu2 = r_m2[je];
                    const float caa = r_sa[je], cbb = r_sb[je], cab = r_ab[je];
                    const float mu1s = mu1 * mu1, mu2s = mu2 * mu2, mu12 = mu1 * mu2;
                    const float sg1 = caa - mu1s, sg2 = cbb - mu2s, sg12 = cab - mu12;
                    const float num = (2.0f * mu12 + C1f) * (2.0f * sg12 + C2f);
                    const float den = (mu1s + mu2s + C1f) * (sg1 + sg2 + C2f);
                    lsum = __builtin_fmaf(num, __builtin_amdgcn_rcpf(den), lsum);
                }
            }
        }
    }

    // block reduction: wave shuffle then LDS across the 4 waves
    float v = lsum;
#pragma unroll
    for (int off = 32; off > 0; off >>= 1) v += __shfl_down(v, off);
    __syncthreads();
    if ((tid & 63) == 0) wsum[tid >> 6] = v;
    __syncthreads();
    if (tid == 0) {
        float bsum = wsum[0] + wsum[1] + wsum[2] + wsum[3];
        atomicAdd(acc_out, (double)bsum);
    }
}

__global__ void ssim_finalize(const double* __restrict__ acc, float* __restrict__ out)
{
    out[0] = 1.0f - (float)(acc[0] * (1.0 / ((double)NIMG * IMG_W * IMG_H)));
}

extern "C" void kernel_launch(void* const* d_in, const int* in_sizes, int n_in,
                              void* d_out, int out_size, void* d_ws, size_t ws_size,
                              hipStream_t stream)
{
    const float* img1 = (const float*)d_in[0];
    const float* img2 = (const float*)d_in[1];
    float* out = (float*)d_out;
    double* accbuf = (double*)d_ws;

    // Gaussian weights exactly as the reference: exp in f64, cast f32, normalize
    GW gw;
    {
        float g[KW];
        double s = 0.0;
        for (int i = 0; i < KW; ++i) {
            int x = i - KW / 2;
            g[i] = (float)exp(-(double)(x * x) / (2.0 * 1.5 * 1.5));
            s += (double)g[i];
        }
        for (int i = 0; i < KW; ++i) gw.w[i] = (float)((double)g[i] / s);
    }

    hipMemsetAsync(accbuf, 0, sizeof(double), stream);
    dim3 grid(IMG_W / TW, IMG_H / TH, NIMG);
    ssim_main<<<grid, 256, 0, stream>>>(img1, img2, accbuf, gw);
    ssim_finalize<<<1, 1, 0, stream>>>(accbuf, out);
}